// Round 7
// baseline (499.782 us; speedup 1.0000x reference)
//
#include <hip/hip_runtime.h>
#include <cmath>

#define RMAXF 5.0f
#define INV_AVG (1.0f/16.0f)
#define SQ4PI 3.5449077018110318f
#define NPTS 4096
#define TAB_SCALE ((float)(NPTS-1)/RMAXF)

// Real sph harmonics l=0..3 (times sqrt(4pi)) of unit vector (x,y,z)
__device__ __forceinline__ void sph16(float x, float y, float z, float* Y){
  float x2=x*x, y2=y*y, z2=z*z;
  Y[0]=SQ4PI*0.28209479177387814f;
  Y[1]=SQ4PI*0.4886025119029199f*y;
  Y[2]=SQ4PI*0.4886025119029199f*z;
  Y[3]=SQ4PI*0.4886025119029199f*x;
  Y[4]=SQ4PI*1.0925484305920792f*x*y;
  Y[5]=SQ4PI*1.0925484305920792f*y*z;
  Y[6]=SQ4PI*0.31539156525252005f*(3.f*z2-1.f);
  Y[7]=SQ4PI*1.0925484305920792f*x*z;
  Y[8]=SQ4PI*0.5462742152960396f*(x2-y2);
  Y[9]=SQ4PI*0.5900435899266435f*y*(3.f*x2-y2);
  Y[10]=SQ4PI*2.890611442640554f*x*y*z;
  Y[11]=SQ4PI*0.4570457994644658f*y*(5.f*z2-1.f);
  Y[12]=SQ4PI*0.3731763325901154f*z*(5.f*z2-3.f);
  Y[13]=SQ4PI*0.4570457994644658f*x*(5.f*z2-1.f);
  Y[14]=SQ4PI*1.445305721320277f*z*(x2-y2);
  Y[15]=SQ4PI*0.5900435899266435f*x*(x2-3.f*y2);
}

// radial basis ef[8] = bess*fcut and d(ef)/dr (table builder only)
__device__ __forceinline__ void radial(float r, float* ef, float* def){
  const float PI_ = 3.14159265358979323846f;
  const float c = 0.6324555320336759f; // sqrt(2/5)
  float xr = r*(1.0f/RMAXF);
  float x2=xr*xr, x3=x2*xr, x5=x3*x2, x6=x5*xr, x7=x6*xr, x8=x7*xr;
  float fcut = 1.f - 28.f*x6 + 48.f*x7 - 21.f*x8;
  float om = 1.f - xr;
  float dfcut = -168.f*x5*om*om*(1.0f/RMAXF);
  float invr = 1.f/r;
  #pragma unroll
  for(int n=1;n<=8;n++){
    float a = (float)n*PI_*(1.0f/RMAXF);
    float ar = a*r;
    float s, co;
    sincosf(ar, &s, &co);
    float b = c*s*invr;
    ef[n-1] = b*fcut;
    def[n-1] = c*(a*co - s*invr)*invr*fcut + b*dfcut;
  }
}

// ---------------- build radial tables: w(r), dw/dr(r), 64 channels --------
__global__ __launch_bounds__(64) void tab_k(
    const float* __restrict__ W_r1, const float* __restrict__ W_r2,
    float* __restrict__ w_tab, float* __restrict__ dw_tab)
{
  __shared__ float s_sil[64], s_ds[64];
  int p = blockIdx.x, lane = threadIdx.x;
  float r = fmaxf((float)p * (RMAXF/(float)(NPTS-1)), 1e-6f);
  float ef[8], def[8];
  radial(r, ef, def);
  float t = 0.f, dt = 0.f;
  #pragma unroll
  for(int j=0;j<8;j++){ t += ef[j]*W_r1[j*64+lane]; dt += def[j]*W_r1[j*64+lane]; }
  float sig = 1.f/(1.f+expf(-t));
  s_sil[lane] = t*sig;
  s_ds[lane]  = sig*(1.f + t*(1.f-sig))*dt;
  __syncthreads();
  float w = 0.f, dw = 0.f;
  for(int j=0;j<64;j++){
    w  += s_sil[j]*W_r2[j*64+lane];
    dw += s_ds[j] *W_r2[j*64+lane];
  }
  w_tab[p*64+lane]  = w;
  dw_tab[p*64+lane] = dw;
}

// ---------------- node embed: h = attrs @ W_embed, e0 atomic per graph ----
__global__ __launch_bounds__(64) void embed_k(
    const float* __restrict__ attrs, const float* __restrict__ W_embed,
    const float* __restrict__ ae, const int* __restrict__ batch,
    float* __restrict__ h, float* __restrict__ e_acc, int N)
{
  int n = blockIdx.x;
  if(n >= N) return;
  int k = threadIdx.x;
  float acc = 0.f;
  #pragma unroll
  for(int s=0;s<10;s++) acc += attrs[n*10+s]*W_embed[s*64+k];
  h[(size_t)n*64+k] = acc;
  if(k==0){
    float e0 = 0.f;
    #pragma unroll
    for(int s=0;s<10;s++) e0 += attrs[n*10+s]*ae[s];
    atomicAdd(&e_acc[batch[n]*2+0], e0);
  }
}

// ---------------- transpose W_mix -> WT[l][c][k] = W_mix[l][k][c] ---------
__global__ void wt_k(const float* __restrict__ W_mix, float* __restrict__ WT){
  int i = threadIdx.x + blockIdx.x*blockDim.x;
  if(i < 16384){
    int l = i >> 12, k = (i >> 6) & 63, c = i & 63;
    WT[l*4096 + c*64 + k] = W_mix[i];
  }
}

// ---------------- CSR build over surviving edges (r < RMAX), key = recv ---
__global__ __launch_bounds__(256) void count_k(
    const float* __restrict__ pos, const float* __restrict__ shifts,
    const int* __restrict__ eidx, int* __restrict__ deg, int E)
{
  int e = blockIdx.x*256 + threadIdx.x;
  if(e >= E) return;
  int snd = eidx[e], rcv = eidx[E+e];
  float vx = pos[rcv*3+0]-pos[snd*3+0]+shifts[e*3+0];
  float vy = pos[rcv*3+1]-pos[snd*3+1]+shifts[e*3+1];
  float vz = pos[rcv*3+2]-pos[snd*3+2]+shifts[e*3+2];
  float r2 = vx*vx+vy*vy+vz*vz + 1e-12f;
  if(r2 < RMAXF*RMAXF) atomicAdd(&deg[rcv], 1);
}

__global__ __launch_bounds__(256) void scan_k(
    const int* __restrict__ deg, int* __restrict__ rowptr,
    int* __restrict__ cursor, int N)
{
  __shared__ int part[256];
  int tid = threadIdx.x;
  int chunk = (N + 255) / 256;
  int begin = tid*chunk, end = begin+chunk < N ? begin+chunk : N;
  int s = 0;
  for(int i=begin;i<end;i++) s += deg[i];
  part[tid] = s;
  __syncthreads();
  for(int off=1; off<256; off<<=1){
    int t = (tid >= off) ? part[tid-off] : 0;
    __syncthreads();
    part[tid] += t;
    __syncthreads();
  }
  int run = part[tid] - s;   // exclusive prefix of this thread's chunk
  for(int i=begin;i<end;i++){
    rowptr[i] = run; cursor[i] = run; run += deg[i];
  }
  if(tid == 255) rowptr[N] = part[255];
}

__global__ __launch_bounds__(256) void scatter_k(
    const float* __restrict__ pos, const float* __restrict__ shifts,
    const int* __restrict__ eidx, int* __restrict__ cursor,
    int* __restrict__ elist, int E)
{
  int e = blockIdx.x*256 + threadIdx.x;
  if(e >= E) return;
  int snd = eidx[e], rcv = eidx[E+e];
  float vx = pos[rcv*3+0]-pos[snd*3+0]+shifts[e*3+0];
  float vy = pos[rcv*3+1]-pos[snd*3+1]+shifts[e*3+1];
  float vz = pos[rcv*3+2]-pos[snd*3+2]+shifts[e*3+2];
  float r2 = vx*vx+vy*vy+vz*vz + 1e-12f;
  if(r2 < RMAXF*RMAXF){
    int p = atomicAdd(&cursor[rcv], 1);
    elist[p] = e;
  }
}

// ---------------- edge forward: one wave per node, table lookup ----------
__global__ __launch_bounds__(256) void fwd_tab(
    const float* __restrict__ pos, const float* __restrict__ shifts,
    const int* __restrict__ eidx, const float* __restrict__ h,
    const float* __restrict__ w_tab,
    const int* __restrict__ rowptr, const int* __restrict__ elist,
    float* __restrict__ A, int N, int E)
{
  int tid = threadIdx.x, ws4 = tid >> 6, lane = tid & 63;
  int n = blockIdx.x*4 + ws4;
  if(n >= N) return;
  int beg = rowptr[n], endp = rowptr[n+1];
  float acc[16];
  #pragma unroll
  for(int lm=0;lm<16;lm++) acc[lm] = 0.f;
  float px = pos[n*3+0], py = pos[n*3+1], pz = pos[n*3+2];
  for(int idx=beg; idx<endp; idx++){
    int e = elist[idx];
    int snd = eidx[e];
    float vx = px - pos[snd*3+0] + shifts[e*3+0];
    float vy = py - pos[snd*3+1] + shifts[e*3+1];
    float vz = pz - pos[snd*3+2] + shifts[e*3+2];
    float r = sqrtf(vx*vx+vy*vy+vz*vz + 1e-12f);
    float invr = 1.f/r;
    float Y[16]; sph16(vx*invr, vy*invr, vz*invr, Y);
    float rs = r*TAB_SCALE;
    int i0 = (int)rs; i0 = i0 < NPTS-2 ? i0 : NPTS-2;
    float fr = rs - (float)i0;
    const float* t0 = w_tab + i0*64 + lane;
    float w0 = t0[0], w1 = t0[64];
    float w = w0 + fr*(w1-w0);
    float wh = w * h[(size_t)snd*64+lane] * INV_AVG;
    #pragma unroll
    for(int lm=0;lm<16;lm++) acc[lm] += wh*Y[lm];
  }
  float* Ab = A + (size_t)n*1024 + lane;
  #pragma unroll
  for(int lm=0;lm<16;lm++) Ab[lm*64] = acc[lm];
}

// ---------------- node: one wave per node, zero LDS, readlane broadcast ---
__device__ __forceinline__ float rl(float v, int k){
  return __uint_as_float(__builtin_amdgcn_readlane(__float_as_uint(v), k));
}

// forward segment for one l: w[k]=W_l[k][lane]; am[lm] = sum_k a[lm][k]*w[k]
#define FWD_L(LIDX, LM0, NL) { \
  _Pragma("unroll") \
  for(int k=0;k<64;k++) w[k] = W_mix[(LIDX)*4096 + k*64 + lane]; \
  _Pragma("unroll") \
  for(int j=0;j<(NL);j++){ \
    float acc = 0.f; \
    _Pragma("unroll") \
    for(int k=0;k<64;k++) acc += rl(a[(LM0)+j],k)*w[k]; \
    am[(LM0)+j] = acc; \
  } }

// backward segment: w[c]=W_l[lane][c] (from WT); gA[lm][lane]=sum_c g[lm][c]*w[c]
#define BWD_L(LIDX, LM0, NL) { \
  _Pragma("unroll") \
  for(int c=0;c<64;c++) w[c] = WT[(LIDX)*4096 + c*64 + lane]; \
  _Pragma("unroll") \
  for(int j=0;j<(NL);j++){ \
    float acc = 0.f; \
    _Pragma("unroll") \
    for(int c=0;c<64;c++) acc += rl(am[(LM0)+j],c)*w[c]; \
    Ab[((LM0)+j)*64 + lane] = acc; \
  } }

__global__ __launch_bounds__(256) void node_k(
    float* __restrict__ A,              // [N][16][64], overwritten with gA
    const float* __restrict__ W_mix,    // [4][64][64]  W[l][k][c]
    const float* __restrict__ WT,       // [4][64][64]  W[l][k][c] -> [l][c][k]
    const float* __restrict__ W_prod,   // [3][64]
    const float* __restrict__ w_ro,     // [64]
    const int* __restrict__ batch, float* __restrict__ e_acc, int N)
{
  int tid = threadIdx.x;
  int n = blockIdx.x*4 + (tid >> 6);
  int lane = tid & 63;
  if(n >= N) return;
  float* Ab = A + (size_t)n*1024;
  float a[16], am[16], w[64];
  #pragma unroll
  for(int lm=0;lm<16;lm++) a[lm] = Ab[lm*64 + lane];

  FWD_L(0,0,1) FWD_L(1,1,3) FWD_L(2,4,5) FWD_L(3,9,7)

  float s_ = 0.f;
  #pragma unroll
  for(int lm=0;lm<16;lm++) s_ += am[lm]*am[lm];
  float a0_ = am[0];
  float wp0 = W_prod[lane], wp1 = W_prod[64+lane], wp2 = W_prod[128+lane];
  float wr = w_ro[lane];
  {
    float B = wp0*a0_ + wp1*s_ + wp2*a0_*s_;
    float v = B*wr;
    #pragma unroll
    for(int off=32; off; off>>=1) v += __shfl_xor(v, off, 64);
    if(lane==0) atomicAdd(&e_acc[batch[n]*2+1], v);
  }
  float gs = wr*(wp1 + wp2*a0_);
  #pragma unroll
  for(int lm=0;lm<16;lm++){
    float g = gs*2.f*am[lm];
    if(lm==0) g += wr*(wp0 + wp2*s_);
    am[lm] = g;     // am now holds gAm
  }

  BWD_L(0,0,1) BWD_L(1,1,3) BWD_L(2,4,5) BWD_L(3,9,7)
}

// ---------------- edge backward: one wave per node, table lookup ----------
__global__ __launch_bounds__(256) void bwd_tab(
    const float* __restrict__ pos, const float* __restrict__ shifts,
    const int* __restrict__ eidx, const float* __restrict__ h,
    const float* __restrict__ w_tab, const float* __restrict__ dw_tab,
    const float* __restrict__ gA,
    const int* __restrict__ rowptr, const int* __restrict__ elist,
    float* __restrict__ forces, int N, int E)
{
  int tid = threadIdx.x, ws4 = tid >> 6, lane = tid & 63;
  int n = blockIdx.x*4 + ws4;
  if(n >= N) return;
  int beg = rowptr[n], endp = rowptr[n+1];
  if(beg == endp) return;
  float gm[16];
  {
    const float* gb = gA + (size_t)n*1024 + lane;
    #pragma unroll
    for(int lm=0;lm<16;lm++) gm[lm] = gb[lm*64]*INV_AVG;
  }
  float px = pos[n*3+0], py = pos[n*3+1], pz = pos[n*3+2];
  float fx=0.f, fy=0.f, fz=0.f;
  const float c1=0.4886025119029199f, c2=1.0925484305920792f, c3=0.31539156525252005f;
  const float c4=0.5462742152960396f, c5=0.5900435899266435f, c6=2.890611442640554f;
  const float c7=0.4570457994644658f, c8=0.3731763325901154f, c9=1.445305721320277f;

  for(int idx=beg; idx<endp; idx++){
    int e = elist[idx];
    int snd = eidx[e];
    float vx = px - pos[snd*3+0] + shifts[e*3+0];
    float vy = py - pos[snd*3+1] + shifts[e*3+1];
    float vz = pz - pos[snd*3+2] + shifts[e*3+2];
    float r = sqrtf(vx*vx+vy*vy+vz*vz + 1e-12f);
    float invr = 1.f/r;
    float x=vx*invr, y=vy*invr, z=vz*invr;
    float Y[16]; sph16(x,y,z,Y);
    float rs = r*TAB_SCALE;
    int i0 = (int)rs; i0 = i0 < NPTS-2 ? i0 : NPTS-2;
    float fr = rs - (float)i0;
    const float* t0 = w_tab  + i0*64 + lane;
    const float* d0 = dw_tab + i0*64 + lane;
    float w    = t0[0] + fr*(t0[64]-t0[0]);
    float dwdr = d0[0] + fr*(d0[64]-d0[0]);
    float hk = h[(size_t)snd*64+lane];
    float wh = w*hk;
    float gw = 0.f;
    #pragma unroll
    for(int lm=0;lm<16;lm++) gw += gm[lm]*Y[lm];
    gw *= hk;
    float x2=x*x, y2=y*y, z2=z*z;
    float fz1 = 5.f*z2-1.f;
    float gxp = c1*gm[3] + c2*(y*gm[4] + z*gm[7]) + 2.f*c4*x*gm[8]
              + 6.f*c5*x*y*gm[9] + c6*y*z*gm[10] + c7*fz1*gm[13]
              + 2.f*c9*x*z*gm[14] + 3.f*c5*(x2-y2)*gm[15];
    float gyp = c1*gm[1] + c2*(x*gm[4] + z*gm[5]) - 2.f*c4*y*gm[8]
              + 3.f*c5*(x2-y2)*gm[9] + c6*x*z*gm[10] + c7*fz1*gm[11]
              - 2.f*c9*y*z*gm[14] - 6.f*c5*x*y*gm[15];
    float gzp = c1*gm[2] + c2*(y*gm[5] + x*gm[7]) + 6.f*c3*z*gm[6]
              + c6*x*y*gm[10] + 10.f*c7*y*z*gm[11] + c8*(15.f*z2-3.f)*gm[12]
              + 10.f*c7*x*z*gm[13] + c9*(x2-y2)*gm[14];
    float gx = gxp*wh*SQ4PI, gy = gyp*wh*SQ4PI, gz = gzp*wh*SQ4PI;
    float grp = gw*dwdr;
    #pragma unroll
    for(int off=32; off; off>>=1){
      gx  += __shfl_xor(gx,  off, 64);
      gy  += __shfl_xor(gy,  off, 64);
      gz  += __shfl_xor(gz,  off, 64);
      grp += __shfl_xor(grp, off, 64);
    }
    float udot = x*gx + y*gy + z*gz;
    float gvx = grp*x + (gx - udot*x)*invr;
    float gvy = grp*y + (gy - udot*y)*invr;
    float gvz = grp*z + (gz - udot*z)*invr;
    fx -= gvx; fy -= gvy; fz -= gvz;
    if(lane==0){
      atomicAdd(&forces[snd*3+0],  gvx);
      atomicAdd(&forces[snd*3+1],  gvy);
      atomicAdd(&forces[snd*3+2],  gvz);
    }
  }
  if(lane==0){
    atomicAdd(&forces[n*3+0], fx);
    atomicAdd(&forces[n*3+1], fy);
    atomicAdd(&forces[n*3+2], fz);
  }
}

// ---------------- finalize ---------------------------------------------
__global__ void fin_k(const float* __restrict__ e_acc, float* __restrict__ out, int G){
  int g = threadIdx.x;
  if(g < G){
    float e0 = e_acc[2*g], e1 = e_acc[2*g+1];
    out[g] = e0+e1;
    out[G + 2*g] = e0;
    out[G + 2*g+1] = e1;
  }
}

extern "C" void kernel_launch(void* const* d_in, const int* in_sizes, int n_in,
                              void* d_out, int out_size, void* d_ws, size_t ws_size,
                              hipStream_t stream) {
  const float* positions  = (const float*)d_in[0];
  const float* node_attrs = (const float*)d_in[1];
  const float* shifts     = (const float*)d_in[2];
  const float* W_embed    = (const float*)d_in[3];
  const float* at_en      = (const float*)d_in[4];
  const float* W_r1       = (const float*)d_in[5];
  const float* W_r2       = (const float*)d_in[6];
  const float* W_mix      = (const float*)d_in[7];
  const float* W_prod     = (const float*)d_in[8];
  const float* w_ro       = (const float*)d_in[9];
  const int*   edge_index = (const int*)d_in[10];
  const int*   batch      = (const int*)d_in[11];

  int N = in_sizes[0]/3;
  int E = in_sizes[10]/2;
  int G = (out_size - 3*N)/3;

  float* out    = (float*)d_out;
  float* A      = (float*)d_ws;                 // N*1024
  float* h      = A + (size_t)N*1024;           // N*64
  float* w_tab  = h + (size_t)N*64;             // NPTS*64
  float* dw_tab = w_tab + (size_t)NPTS*64;      // NPTS*64
  float* WT     = dw_tab + (size_t)NPTS*64;     // 16384
  float* eacc   = WT + 16384;                   // 2G
  int*   deg    = (int*)(eacc + 2*G);           // N
  int*   rowptr = deg + N;                      // N+1
  int*   cursor = rowptr + N + 1;               // N
  int*   elist  = cursor + N;                   // E

  hipMemsetAsync(d_out, 0, (size_t)out_size*sizeof(float), stream);
  hipMemsetAsync(eacc, 0, (size_t)2*G*sizeof(float), stream);
  hipMemsetAsync(deg, 0, (size_t)N*sizeof(int), stream);

  embed_k<<<N, 64, 0, stream>>>(node_attrs, W_embed, at_en, batch, h, eacc, N);
  tab_k<<<NPTS, 64, 0, stream>>>(W_r1, W_r2, w_tab, dw_tab);
  wt_k<<<64, 256, 0, stream>>>(W_mix, WT);
  count_k<<<(E+255)/256, 256, 0, stream>>>(positions, shifts, edge_index, deg, E);
  scan_k<<<1, 256, 0, stream>>>(deg, rowptr, cursor, N);
  scatter_k<<<(E+255)/256, 256, 0, stream>>>(positions, shifts, edge_index, cursor, elist, E);
  fwd_tab<<<(N+3)/4, 256, 0, stream>>>(positions, shifts, edge_index, h, w_tab, rowptr, elist, A, N, E);
  node_k<<<(N+3)/4, 256, 0, stream>>>(A, W_mix, WT, W_prod, w_ro, batch, eacc, N);
  bwd_tab<<<(N+3)/4, 256, 0, stream>>>(positions, shifts, edge_index, h, w_tab, dw_tab, A, rowptr, elist, out + 3*G, N, E);
  fin_k<<<1, 64, 0, stream>>>(eacc, out, G);
}

// Round 8
// 406.721 us; speedup vs baseline: 1.2288x; 1.2288x over previous
//
#include <hip/hip_runtime.h>
#include <cmath>

#define RMAXF 5.0f
#define INV_AVG (1.0f/16.0f)
#define SQ4PI 3.5449077018110318f
#define NPTS 4096
#define TAB_SCALE ((float)(NPTS-1)/RMAXF)

// Real sph harmonics l=0..3 (times sqrt(4pi)) of unit vector (x,y,z)
__device__ __forceinline__ void sph16(float x, float y, float z, float* Y){
  float x2=x*x, y2=y*y, z2=z*z;
  Y[0]=SQ4PI*0.28209479177387814f;
  Y[1]=SQ4PI*0.4886025119029199f*y;
  Y[2]=SQ4PI*0.4886025119029199f*z;
  Y[3]=SQ4PI*0.4886025119029199f*x;
  Y[4]=SQ4PI*1.0925484305920792f*x*y;
  Y[5]=SQ4PI*1.0925484305920792f*y*z;
  Y[6]=SQ4PI*0.31539156525252005f*(3.f*z2-1.f);
  Y[7]=SQ4PI*1.0925484305920792f*x*z;
  Y[8]=SQ4PI*0.5462742152960396f*(x2-y2);
  Y[9]=SQ4PI*0.5900435899266435f*y*(3.f*x2-y2);
  Y[10]=SQ4PI*2.890611442640554f*x*y*z;
  Y[11]=SQ4PI*0.4570457994644658f*y*(5.f*z2-1.f);
  Y[12]=SQ4PI*0.3731763325901154f*z*(5.f*z2-3.f);
  Y[13]=SQ4PI*0.4570457994644658f*x*(5.f*z2-1.f);
  Y[14]=SQ4PI*1.445305721320277f*z*(x2-y2);
  Y[15]=SQ4PI*0.5900435899266435f*x*(x2-3.f*y2);
}

// radial basis ef[8] = bess*fcut and d(ef)/dr (table builder only)
__device__ __forceinline__ void radial(float r, float* ef, float* def){
  const float PI_ = 3.14159265358979323846f;
  const float c = 0.6324555320336759f; // sqrt(2/5)
  float xr = r*(1.0f/RMAXF);
  float x2=xr*xr, x3=x2*xr, x5=x3*x2, x6=x5*xr, x7=x6*xr, x8=x7*xr;
  float fcut = 1.f - 28.f*x6 + 48.f*x7 - 21.f*x8;
  float om = 1.f - xr;
  float dfcut = -168.f*x5*om*om*(1.0f/RMAXF);
  float invr = 1.f/r;
  #pragma unroll
  for(int n=1;n<=8;n++){
    float a = (float)n*PI_*(1.0f/RMAXF);
    float ar = a*r;
    float s, co;
    sincosf(ar, &s, &co);
    float b = c*s*invr;
    ef[n-1] = b*fcut;
    def[n-1] = c*(a*co - s*invr)*invr*fcut + b*dfcut;
  }
}

__device__ __forceinline__ unsigned int bf16rne(float x){
  unsigned int u = __float_as_uint(x);
  u += 0x7fffu + ((u>>16)&1u);
  return u>>16;
}

// ---------------- build radial tables: w(r), dw/dr(r), 64 channels --------
__global__ __launch_bounds__(64) void tab_k(
    const float* __restrict__ W_r1, const float* __restrict__ W_r2,
    float* __restrict__ w_tab, float* __restrict__ dw_tab)
{
  __shared__ float s_sil[64], s_ds[64];
  int p = blockIdx.x, lane = threadIdx.x;
  float r = fmaxf((float)p * (RMAXF/(float)(NPTS-1)), 1e-6f);
  float ef[8], def[8];
  radial(r, ef, def);
  float t = 0.f, dt = 0.f;
  #pragma unroll
  for(int j=0;j<8;j++){ t += ef[j]*W_r1[j*64+lane]; dt += def[j]*W_r1[j*64+lane]; }
  float sig = 1.f/(1.f+expf(-t));
  s_sil[lane] = t*sig;
  s_ds[lane]  = sig*(1.f + t*(1.f-sig))*dt;
  __syncthreads();
  float w = 0.f, dw = 0.f;
  for(int j=0;j<64;j++){
    w  += s_sil[j]*W_r2[j*64+lane];
    dw += s_ds[j] *W_r2[j*64+lane];
  }
  w_tab[p*64+lane]  = w;
  dw_tab[p*64+lane] = dw;
}

// ---------------- node embed: h = attrs @ W_embed, e0 atomic per graph ----
__global__ __launch_bounds__(64) void embed_k(
    const float* __restrict__ attrs, const float* __restrict__ W_embed,
    const float* __restrict__ ae, const int* __restrict__ batch,
    float* __restrict__ h, float* __restrict__ e_acc, int N)
{
  int n = blockIdx.x;
  if(n >= N) return;
  int k = threadIdx.x;
  float acc = 0.f;
  #pragma unroll
  for(int s=0;s<10;s++) acc += attrs[n*10+s]*W_embed[s*64+k];
  h[(size_t)n*64+k] = acc;
  if(k==0){
    float e0 = 0.f;
    #pragma unroll
    for(int s=0;s<10;s++) e0 += attrs[n*10+s]*ae[s];
    atomicAdd(&e_acc[batch[n]*2+0], e0);
  }
}

// ---------------- pack W_mix to bf16 k-pairs: Wp[l][c][kp] ----------------
__global__ void pack_k(const float* __restrict__ W_mix, unsigned int* __restrict__ Wp){
  int i = threadIdx.x + blockIdx.x*blockDim.x;
  if(i < 8192){
    int l = i >> 11, c = (i >> 5) & 63, kp = i & 31;
    float w0 = W_mix[l*4096 + (2*kp  )*64 + c];
    float w1 = W_mix[l*4096 + (2*kp+1)*64 + c];
    Wp[i] = bf16rne(w0) | (bf16rne(w1) << 16);
  }
}

// ---------------- CSR build over surviving edges (r < RMAX), key = recv ---
__global__ __launch_bounds__(256) void count_k(
    const float* __restrict__ pos, const float* __restrict__ shifts,
    const int* __restrict__ eidx, int* __restrict__ deg, int E)
{
  int e = blockIdx.x*256 + threadIdx.x;
  if(e >= E) return;
  int snd = eidx[e], rcv = eidx[E+e];
  float vx = pos[rcv*3+0]-pos[snd*3+0]+shifts[e*3+0];
  float vy = pos[rcv*3+1]-pos[snd*3+1]+shifts[e*3+1];
  float vz = pos[rcv*3+2]-pos[snd*3+2]+shifts[e*3+2];
  float r2 = vx*vx+vy*vy+vz*vz + 1e-12f;
  if(r2 < RMAXF*RMAXF) atomicAdd(&deg[rcv], 1);
}

__global__ __launch_bounds__(256) void scan_k(
    const int* __restrict__ deg, int* __restrict__ rowptr,
    int* __restrict__ cursor, int N)
{
  __shared__ int part[256];
  int tid = threadIdx.x;
  int chunk = (N + 255) / 256;
  int begin = tid*chunk, end = begin+chunk < N ? begin+chunk : N;
  int s = 0;
  for(int i=begin;i<end;i++) s += deg[i];
  part[tid] = s;
  __syncthreads();
  for(int off=1; off<256; off<<=1){
    int t = (tid >= off) ? part[tid-off] : 0;
    __syncthreads();
    part[tid] += t;
    __syncthreads();
  }
  int run = part[tid] - s;   // exclusive prefix of this thread's chunk
  for(int i=begin;i<end;i++){
    rowptr[i] = run; cursor[i] = run; run += deg[i];
  }
  if(tid == 255) rowptr[N] = part[255];
}

__global__ __launch_bounds__(256) void scatter_k(
    const float* __restrict__ pos, const float* __restrict__ shifts,
    const int* __restrict__ eidx, int* __restrict__ cursor,
    int* __restrict__ elist, int E)
{
  int e = blockIdx.x*256 + threadIdx.x;
  if(e >= E) return;
  int snd = eidx[e], rcv = eidx[E+e];
  float vx = pos[rcv*3+0]-pos[snd*3+0]+shifts[e*3+0];
  float vy = pos[rcv*3+1]-pos[snd*3+1]+shifts[e*3+1];
  float vz = pos[rcv*3+2]-pos[snd*3+2]+shifts[e*3+2];
  float r2 = vx*vx+vy*vy+vz*vz + 1e-12f;
  if(r2 < RMAXF*RMAXF){
    int p = atomicAdd(&cursor[rcv], 1);
    elist[p] = e;
  }
}

// ---------------- edge forward: one wave per node, table lookup ----------
__global__ __launch_bounds__(256) void fwd_tab(
    const float* __restrict__ pos, const float* __restrict__ shifts,
    const int* __restrict__ eidx, const float* __restrict__ h,
    const float* __restrict__ w_tab,
    const int* __restrict__ rowptr, const int* __restrict__ elist,
    float* __restrict__ A, int N, int E)
{
  int tid = threadIdx.x, ws4 = tid >> 6, lane = tid & 63;
  int n = blockIdx.x*4 + ws4;
  if(n >= N) return;
  int beg = rowptr[n], endp = rowptr[n+1];
  float acc[16];
  #pragma unroll
  for(int lm=0;lm<16;lm++) acc[lm] = 0.f;
  float px = pos[n*3+0], py = pos[n*3+1], pz = pos[n*3+2];
  for(int idx=beg; idx<endp; idx++){
    int e = elist[idx];
    int snd = eidx[e];
    float vx = px - pos[snd*3+0] + shifts[e*3+0];
    float vy = py - pos[snd*3+1] + shifts[e*3+1];
    float vz = pz - pos[snd*3+2] + shifts[e*3+2];
    float r = sqrtf(vx*vx+vy*vy+vz*vz + 1e-12f);
    float invr = 1.f/r;
    float Y[16]; sph16(vx*invr, vy*invr, vz*invr, Y);
    float rs = r*TAB_SCALE;
    int i0 = (int)rs; i0 = i0 < NPTS-2 ? i0 : NPTS-2;
    float fr = rs - (float)i0;
    const float* t0 = w_tab + i0*64 + lane;
    float w0 = t0[0], w1 = t0[64];
    float w = w0 + fr*(w1-w0);
    float wh = w * h[(size_t)snd*64+lane] * INV_AVG;
    #pragma unroll
    for(int lm=0;lm<16;lm++) acc[lm] += wh*Y[lm];
  }
  float* Ab = A + (size_t)n*1024 + lane;
  #pragma unroll
  for(int lm=0;lm<16;lm++) Ab[lm*64] = acc[lm];
}

// ---------------- node: bf16-packed W in padded LDS, conflict-free both dirs
// sWp[l][c][kp], row stride 33: word bank = (c + kp) % 32.
//  fwd (lane=c): reads its row -> 2 lanes/bank, free.
//  bwd (lane=k): reads column kp=k>>1 -> adjacent lanes broadcast, free.
__global__ __launch_bounds__(256) void node_k(
    float* __restrict__ A,              // [N][16][64], overwritten with gA
    const unsigned int* __restrict__ Wp,// [4][64][32] bf16 k-pairs
    const float* __restrict__ W_prod,   // [3][64]
    const float* __restrict__ w_ro,     // [64]
    const int* __restrict__ batch, float* __restrict__ e_acc, int N)
{
  __shared__ unsigned int sWp[4*64*33];
  __shared__ float sA[1024];
  __shared__ float sG[1024];
  __shared__ float sS[4][64];
  __shared__ float sA0[64];

  const int tid = threadIdx.x;
  const int lane = tid & 63;
  const int lmg = tid >> 6;

  for(int i = tid; i < 8192; i += 256){
    int l = i >> 11, c = (i >> 5) & 63, kp = i & 31;
    sWp[l*2112 + c*33 + kp] = Wp[i];
  }

  const int lm0 = lmg*4;
  // l per slot: slot0 = l_of(lm0), slots1-3 = l_of(lm0+1)
  const int lA = (lmg==0)?0:((lmg==3)?3:2);
  const int lB = (lmg==0)?1:((lmg==1)?2:3);

  const float wp0 = W_prod[lane], wp1 = W_prod[64+lane], wp2 = W_prod[128+lane];
  const float wr = w_ro[lane];

  const unsigned int* rowA = &sWp[lA*2112 + lane*33];
  const unsigned int* rowB = &sWp[lB*2112 + lane*33];
  const unsigned int* colA = &sWp[lA*2112 + (lane>>1)];
  const unsigned int* colB = &sWp[lB*2112 + (lane>>1)];
  const bool hi = (lane & 1);

  const float4* a0p = reinterpret_cast<const float4*>(&sA[(lm0+0)*64]);
  const float4* a1p = reinterpret_cast<const float4*>(&sA[(lm0+1)*64]);
  const float4* a2p = reinterpret_cast<const float4*>(&sA[(lm0+2)*64]);
  const float4* a3p = reinterpret_cast<const float4*>(&sA[(lm0+3)*64]);
  const float4* g0p = reinterpret_cast<const float4*>(&sG[(lm0+0)*64]);
  const float4* g1p = reinterpret_cast<const float4*>(&sG[(lm0+1)*64]);
  const float4* g2p = reinterpret_cast<const float4*>(&sG[(lm0+2)*64]);
  const float4* g3p = reinterpret_cast<const float4*>(&sG[(lm0+3)*64]);

  for(int n = blockIdx.x; n < N; n += gridDim.x){
    reinterpret_cast<float4*>(sA)[tid] =
        reinterpret_cast<const float4*>(A + (size_t)n*1024)[tid];
    __syncthreads();

    // forward: am[slot] = sum_k sA[lm][k] * W[l][k][c=lane]
    float am0=0.f, am1=0.f, am2=0.f, am3=0.f;
    #pragma unroll
    for(int kb=0; kb<16; kb++){
      float4 a0 = a0p[kb], a1 = a1p[kb], a2 = a2p[kb], a3 = a3p[kb];
      unsigned int uA0 = rowA[kb*2], uA1 = rowA[kb*2+1];
      unsigned int uB0 = rowB[kb*2], uB1 = rowB[kb*2+1];
      float wa0 = __uint_as_float(uA0<<16), wa1 = __uint_as_float(uA0 & 0xffff0000u);
      float wa2 = __uint_as_float(uA1<<16), wa3 = __uint_as_float(uA1 & 0xffff0000u);
      float wb0 = __uint_as_float(uB0<<16), wb1 = __uint_as_float(uB0 & 0xffff0000u);
      float wb2 = __uint_as_float(uB1<<16), wb3 = __uint_as_float(uB1 & 0xffff0000u);
      am0 += a0.x*wa0 + a0.y*wa1 + a0.z*wa2 + a0.w*wa3;
      am1 += a1.x*wb0 + a1.y*wb1 + a1.z*wb2 + a1.w*wb3;
      am2 += a2.x*wb0 + a2.y*wb1 + a2.z*wb2 + a2.w*wb3;
      am3 += a3.x*wb0 + a3.y*wb1 + a3.z*wb2 + a3.w*wb3;
    }

    sS[lmg][lane] = am0*am0 + am1*am1 + am2*am2 + am3*am3;
    if(lmg==0) sA0[lane] = am0;
    __syncthreads();

    float s_  = sS[0][lane] + sS[1][lane] + sS[2][lane] + sS[3][lane];
    float a0_ = sA0[lane];
    if(lmg==0){
      float B = wp0*a0_ + wp1*s_ + wp2*a0_*s_;
      float v = B*wr;
      #pragma unroll
      for(int off=32; off; off>>=1) v += __shfl_xor(v, off, 64);
      if(lane==0) atomicAdd(&e_acc[batch[n]*2+1], v);
    }
    float gs = wr*(wp1 + wp2*a0_);
    {
      float g0 = gs*2.f*am0 + ((lmg==0) ? wr*(wp0 + wp2*s_) : 0.f);
      sG[(lm0+0)*64+lane] = g0;
      sG[(lm0+1)*64+lane] = gs*2.f*am1;
      sG[(lm0+2)*64+lane] = gs*2.f*am2;
      sG[(lm0+3)*64+lane] = gs*2.f*am3;
    }
    __syncthreads();

    // backward: ga[slot][k=lane] = sum_c sG[lm][c] * W[l][k][c]
    float ga0=0.f, ga1=0.f, ga2=0.f, ga3=0.f;
    #pragma unroll
    for(int cb=0; cb<16; cb++){
      float g0[4], g1[4], g2[4], g3[4];
      *reinterpret_cast<float4*>(g0) = g0p[cb];
      *reinterpret_cast<float4*>(g1) = g1p[cb];
      *reinterpret_cast<float4*>(g2) = g2p[cb];
      *reinterpret_cast<float4*>(g3) = g3p[cb];
      #pragma unroll
      for(int j=0;j<4;j++){
        int c = cb*4 + j;
        unsigned int ua = colA[c*33];
        unsigned int ub = colB[c*33];
        float wa = hi ? __uint_as_float(ua & 0xffff0000u) : __uint_as_float(ua<<16);
        float wb = hi ? __uint_as_float(ub & 0xffff0000u) : __uint_as_float(ub<<16);
        ga0 += g0[j]*wa;
        ga1 += g1[j]*wb;
        ga2 += g2[j]*wb;
        ga3 += g3[j]*wb;
      }
    }
    float* dst = A + (size_t)n*1024;
    dst[(lm0+0)*64 + lane] = ga0;
    dst[(lm0+1)*64 + lane] = ga1;
    dst[(lm0+2)*64 + lane] = ga2;
    dst[(lm0+3)*64 + lane] = ga3;
    __syncthreads();   // protect sA/sG before next iteration
  }
}

// ---------------- edge backward: one wave per node, table lookup ----------
__global__ __launch_bounds__(256) void bwd_tab(
    const float* __restrict__ pos, const float* __restrict__ shifts,
    const int* __restrict__ eidx, const float* __restrict__ h,
    const float* __restrict__ w_tab, const float* __restrict__ dw_tab,
    const float* __restrict__ gA,
    const int* __restrict__ rowptr, const int* __restrict__ elist,
    float* __restrict__ forces, int N, int E)
{
  int tid = threadIdx.x, ws4 = tid >> 6, lane = tid & 63;
  int n = blockIdx.x*4 + ws4;
  if(n >= N) return;
  int beg = rowptr[n], endp = rowptr[n+1];
  if(beg == endp) return;
  float gm[16];
  {
    const float* gb = gA + (size_t)n*1024 + lane;
    #pragma unroll
    for(int lm=0;lm<16;lm++) gm[lm] = gb[lm*64]*INV_AVG;
  }
  float px = pos[n*3+0], py = pos[n*3+1], pz = pos[n*3+2];
  float fx=0.f, fy=0.f, fz=0.f;
  const float c1=0.4886025119029199f, c2=1.0925484305920792f, c3=0.31539156525252005f;
  const float c4=0.5462742152960396f, c5=0.5900435899266435f, c6=2.890611442640554f;
  const float c7=0.4570457994644658f, c8=0.3731763325901154f, c9=1.445305721320277f;

  for(int idx=beg; idx<endp; idx++){
    int e = elist[idx];
    int snd = eidx[e];
    float vx = px - pos[snd*3+0] + shifts[e*3+0];
    float vy = py - pos[snd*3+1] + shifts[e*3+1];
    float vz = pz - pos[snd*3+2] + shifts[e*3+2];
    float r = sqrtf(vx*vx+vy*vy+vz*vz + 1e-12f);
    float invr = 1.f/r;
    float x=vx*invr, y=vy*invr, z=vz*invr;
    float Y[16]; sph16(x,y,z,Y);
    float rs = r*TAB_SCALE;
    int i0 = (int)rs; i0 = i0 < NPTS-2 ? i0 : NPTS-2;
    float fr = rs - (float)i0;
    const float* t0 = w_tab  + i0*64 + lane;
    const float* d0 = dw_tab + i0*64 + lane;
    float w    = t0[0] + fr*(t0[64]-t0[0]);
    float dwdr = d0[0] + fr*(d0[64]-d0[0]);
    float hk = h[(size_t)snd*64+lane];
    float wh = w*hk;
    float gw = 0.f;
    #pragma unroll
    for(int lm=0;lm<16;lm++) gw += gm[lm]*Y[lm];
    gw *= hk;
    float x2=x*x, y2=y*y, z2=z*z;
    float fz1 = 5.f*z2-1.f;
    float gxp = c1*gm[3] + c2*(y*gm[4] + z*gm[7]) + 2.f*c4*x*gm[8]
              + 6.f*c5*x*y*gm[9] + c6*y*z*gm[10] + c7*fz1*gm[13]
              + 2.f*c9*x*z*gm[14] + 3.f*c5*(x2-y2)*gm[15];
    float gyp = c1*gm[1] + c2*(x*gm[4] + z*gm[5]) - 2.f*c4*y*gm[8]
              + 3.f*c5*(x2-y2)*gm[9] + c6*x*z*gm[10] + c7*fz1*gm[11]
              - 2.f*c9*y*z*gm[14] - 6.f*c5*x*y*gm[15];
    float gzp = c1*gm[2] + c2*(y*gm[5] + x*gm[7]) + 6.f*c3*z*gm[6]
              + c6*x*y*gm[10] + 10.f*c7*y*z*gm[11] + c8*(15.f*z2-3.f)*gm[12]
              + 10.f*c7*x*z*gm[13] + c9*(x2-y2)*gm[14];
    float gx = gxp*wh*SQ4PI, gy = gyp*wh*SQ4PI, gz = gzp*wh*SQ4PI;
    float grp = gw*dwdr;
    #pragma unroll
    for(int off=32; off; off>>=1){
      gx  += __shfl_xor(gx,  off, 64);
      gy  += __shfl_xor(gy,  off, 64);
      gz  += __shfl_xor(gz,  off, 64);
      grp += __shfl_xor(grp, off, 64);
    }
    float udot = x*gx + y*gy + z*gz;
    float gvx = grp*x + (gx - udot*x)*invr;
    float gvy = grp*y + (gy - udot*y)*invr;
    float gvz = grp*z + (gz - udot*z)*invr;
    fx -= gvx; fy -= gvy; fz -= gvz;
    if(lane==0){
      atomicAdd(&forces[snd*3+0],  gvx);
      atomicAdd(&forces[snd*3+1],  gvy);
      atomicAdd(&forces[snd*3+2],  gvz);
    }
  }
  if(lane==0){
    atomicAdd(&forces[n*3+0], fx);
    atomicAdd(&forces[n*3+1], fy);
    atomicAdd(&forces[n*3+2], fz);
  }
}

// ---------------- finalize ---------------------------------------------
__global__ void fin_k(const float* __restrict__ e_acc, float* __restrict__ out, int G){
  int g = threadIdx.x;
  if(g < G){
    float e0 = e_acc[2*g], e1 = e_acc[2*g+1];
    out[g] = e0+e1;
    out[G + 2*g] = e0;
    out[G + 2*g+1] = e1;
  }
}

extern "C" void kernel_launch(void* const* d_in, const int* in_sizes, int n_in,
                              void* d_out, int out_size, void* d_ws, size_t ws_size,
                              hipStream_t stream) {
  const float* positions  = (const float*)d_in[0];
  const float* node_attrs = (const float*)d_in[1];
  const float* shifts     = (const float*)d_in[2];
  const float* W_embed    = (const float*)d_in[3];
  const float* at_en      = (const float*)d_in[4];
  const float* W_r1       = (const float*)d_in[5];
  const float* W_r2       = (const float*)d_in[6];
  const float* W_mix      = (const float*)d_in[7];
  const float* W_prod     = (const float*)d_in[8];
  const float* w_ro       = (const float*)d_in[9];
  const int*   edge_index = (const int*)d_in[10];
  const int*   batch      = (const int*)d_in[11];

  int N = in_sizes[0]/3;
  int E = in_sizes[10]/2;
  int G = (out_size - 3*N)/3;

  float* out    = (float*)d_out;
  float* A      = (float*)d_ws;                 // N*1024
  float* h      = A + (size_t)N*1024;           // N*64
  float* w_tab  = h + (size_t)N*64;             // NPTS*64
  float* dw_tab = w_tab + (size_t)NPTS*64;      // NPTS*64
  unsigned int* Wp = (unsigned int*)(dw_tab + (size_t)NPTS*64); // 8192
  float* eacc   = (float*)(Wp + 8192);          // 2G
  int*   deg    = (int*)(eacc + 2*G);           // N
  int*   rowptr = deg + N;                      // N+1
  int*   cursor = rowptr + N + 1;               // N
  int*   elist  = cursor + N;                   // E

  hipMemsetAsync(d_out, 0, (size_t)out_size*sizeof(float), stream);
  hipMemsetAsync(eacc, 0, (size_t)2*G*sizeof(float), stream);
  hipMemsetAsync(deg, 0, (size_t)N*sizeof(int), stream);

  embed_k<<<N, 64, 0, stream>>>(node_attrs, W_embed, at_en, batch, h, eacc, N);
  tab_k<<<NPTS, 64, 0, stream>>>(W_r1, W_r2, w_tab, dw_tab);
  pack_k<<<32, 256, 0, stream>>>(W_mix, Wp);
  count_k<<<(E+255)/256, 256, 0, stream>>>(positions, shifts, edge_index, deg, E);
  scan_k<<<1, 256, 0, stream>>>(deg, rowptr, cursor, N);
  scatter_k<<<(E+255)/256, 256, 0, stream>>>(positions, shifts, edge_index, cursor, elist, E);
  fwd_tab<<<(N+3)/4, 256, 0, stream>>>(positions, shifts, edge_index, h, w_tab, rowptr, elist, A, N, E);
  node_k<<<768, 256, 0, stream>>>(A, Wp, W_prod, w_ro, batch, eacc, N);
  bwd_tab<<<(N+3)/4, 256, 0, stream>>>(positions, shifts, edge_index, h, w_tab, dw_tab, A, rowptr, elist, out + 3*G, N, E);
  fin_k<<<1, 64, 0, stream>>>(eacc, out, G);
}

// Round 10
// 367.849 us; speedup vs baseline: 1.3587x; 1.1057x over previous
//
#include <hip/hip_runtime.h>
#include <cmath>

#define RMAXF 5.0f
#define INV_AVG (1.0f/16.0f)
#define SQ4PI 3.5449077018110318f
#define NPTS 4096
#define TAB_SCALE ((float)(NPTS-1)/RMAXF)

typedef _Float16 h2 __attribute__((ext_vector_type(2)));

__device__ __forceinline__ h2 as_h2(unsigned int u){ h2 r; __builtin_memcpy(&r,&u,4); return r; }
__device__ __forceinline__ unsigned int as_u32(h2 h){ unsigned int u; __builtin_memcpy(&u,&h,4); return u; }
__device__ __forceinline__ unsigned int pk16(float a, float b){
  h2 t; t[0] = (_Float16)a; t[1] = (_Float16)b; return as_u32(t);
}
__device__ __forceinline__ float fdot2(h2 a, h2 b, float c){ return __builtin_amdgcn_fdot2(a,b,c,false); }

// Real sph harmonics l=0..3 (times sqrt(4pi)) of unit vector (x,y,z)
__device__ __forceinline__ void sph16(float x, float y, float z, float* Y){
  float x2=x*x, y2=y*y, z2=z*z;
  Y[0]=SQ4PI*0.28209479177387814f;
  Y[1]=SQ4PI*0.4886025119029199f*y;
  Y[2]=SQ4PI*0.4886025119029199f*z;
  Y[3]=SQ4PI*0.4886025119029199f*x;
  Y[4]=SQ4PI*1.0925484305920792f*x*y;
  Y[5]=SQ4PI*1.0925484305920792f*y*z;
  Y[6]=SQ4PI*0.31539156525252005f*(3.f*z2-1.f);
  Y[7]=SQ4PI*1.0925484305920792f*x*z;
  Y[8]=SQ4PI*0.5462742152960396f*(x2-y2);
  Y[9]=SQ4PI*0.5900435899266435f*y*(3.f*x2-y2);
  Y[10]=SQ4PI*2.890611442640554f*x*y*z;
  Y[11]=SQ4PI*0.4570457994644658f*y*(5.f*z2-1.f);
  Y[12]=SQ4PI*0.3731763325901154f*z*(5.f*z2-3.f);
  Y[13]=SQ4PI*0.4570457994644658f*x*(5.f*z2-1.f);
  Y[14]=SQ4PI*1.445305721320277f*z*(x2-y2);
  Y[15]=SQ4PI*0.5900435899266435f*x*(x2-3.f*y2);
}

// radial basis ef[8] = bess*fcut and d(ef)/dr (table builder only)
__device__ __forceinline__ void radial(float r, float* ef, float* def){
  const float PI_ = 3.14159265358979323846f;
  const float c = 0.6324555320336759f; // sqrt(2/5)
  float xr = r*(1.0f/RMAXF);
  float x2=xr*xr, x3=x2*xr, x5=x3*x2, x6=x5*xr, x7=x6*xr, x8=x7*xr;
  float fcut = 1.f - 28.f*x6 + 48.f*x7 - 21.f*x8;
  float om = 1.f - xr;
  float dfcut = -168.f*x5*om*om*(1.0f/RMAXF);
  float invr = 1.f/r;
  #pragma unroll
  for(int n=1;n<=8;n++){
    float a = (float)n*PI_*(1.0f/RMAXF);
    float ar = a*r;
    float s, co;
    sincosf(ar, &s, &co);
    float b = c*s*invr;
    ef[n-1] = b*fcut;
    def[n-1] = c*(a*co - s*invr)*invr*fcut + b*dfcut;
  }
}

// ---------------- build radial tables: w(r), dw/dr(r), 64 channels --------
__global__ __launch_bounds__(64) void tab_k(
    const float* __restrict__ W_r1, const float* __restrict__ W_r2,
    float* __restrict__ w_tab, float* __restrict__ dw_tab)
{
  __shared__ float s_sil[64], s_ds[64];
  int p = blockIdx.x, lane = threadIdx.x;
  float r = fmaxf((float)p * (RMAXF/(float)(NPTS-1)), 1e-6f);
  float ef[8], def[8];
  radial(r, ef, def);
  float t = 0.f, dt = 0.f;
  #pragma unroll
  for(int j=0;j<8;j++){ t += ef[j]*W_r1[j*64+lane]; dt += def[j]*W_r1[j*64+lane]; }
  float sig = 1.f/(1.f+expf(-t));
  s_sil[lane] = t*sig;
  s_ds[lane]  = sig*(1.f + t*(1.f-sig))*dt;
  __syncthreads();
  float w = 0.f, dw = 0.f;
  for(int j=0;j<64;j++){
    w  += s_sil[j]*W_r2[j*64+lane];
    dw += s_ds[j] *W_r2[j*64+lane];
  }
  w_tab[p*64+lane]  = w;
  dw_tab[p*64+lane] = dw;
}

// ---------------- node embed: h = attrs @ W_embed, e0 atomic per graph ----
__global__ __launch_bounds__(64) void embed_k(
    const float* __restrict__ attrs, const float* __restrict__ W_embed,
    const float* __restrict__ ae, const int* __restrict__ batch,
    float* __restrict__ h, float* __restrict__ e_acc, int N)
{
  int n = blockIdx.x;
  if(n >= N) return;
  int k = threadIdx.x;
  float acc = 0.f;
  #pragma unroll
  for(int s=0;s<10;s++) acc += attrs[n*10+s]*W_embed[s*64+k];
  h[(size_t)n*64+k] = acc;
  if(k==0){
    float e0 = 0.f;
    #pragma unroll
    for(int s=0;s<10;s++) e0 += attrs[n*10+s]*ae[s];
    atomicAdd(&e_acc[batch[n]*2+0], e0);
  }
}

// ---------------- pack W_mix as f16 pairs, both orientations --------------
// Wpc[l][c][kp] = half2(W[l][2kp][c], W[l][2kp+1][c])   (fwd: lane=c column)
// Wpr[l][k][cp] = half2(W[l][k][2cp], W[l][k][2cp+1])   (bwd: lane=k row)
__global__ void pack_k(const float* __restrict__ W_mix,
                       unsigned int* __restrict__ Wpc,
                       unsigned int* __restrict__ Wpr){
  int i = threadIdx.x + blockIdx.x*blockDim.x;
  if(i < 8192){
    int l = i >> 11, a = (i >> 5) & 63, p = i & 31;
    Wpc[i] = pk16(W_mix[l*4096 + (2*p)*64 + a], W_mix[l*4096 + (2*p+1)*64 + a]);
    Wpr[i] = pk16(W_mix[l*4096 + a*64 + 2*p], W_mix[l*4096 + a*64 + 2*p+1]);
  }
}

// ---------------- CSR build over surviving edges (r < RMAX), key = recv ---
__global__ __launch_bounds__(256) void count_k(
    const float* __restrict__ pos, const float* __restrict__ shifts,
    const int* __restrict__ eidx, int* __restrict__ deg, int E)
{
  int e = blockIdx.x*256 + threadIdx.x;
  if(e >= E) return;
  int snd = eidx[e], rcv = eidx[E+e];
  float vx = pos[rcv*3+0]-pos[snd*3+0]+shifts[e*3+0];
  float vy = pos[rcv*3+1]-pos[snd*3+1]+shifts[e*3+1];
  float vz = pos[rcv*3+2]-pos[snd*3+2]+shifts[e*3+2];
  float r2 = vx*vx+vy*vy+vz*vz + 1e-12f;
  if(r2 < RMAXF*RMAXF) atomicAdd(&deg[rcv], 1);
}

__global__ __launch_bounds__(256) void scan_k(
    const int* __restrict__ deg, int* __restrict__ rowptr,
    int* __restrict__ cursor, int N)
{
  __shared__ int part[256];
  int tid = threadIdx.x;
  int chunk = (N + 255) / 256;
  int begin = tid*chunk, end = begin+chunk < N ? begin+chunk : N;
  int s = 0;
  for(int i=begin;i<end;i++) s += deg[i];
  part[tid] = s;
  __syncthreads();
  for(int off=1; off<256; off<<=1){
    int t = (tid >= off) ? part[tid-off] : 0;
    __syncthreads();
    part[tid] += t;
    __syncthreads();
  }
  int run = part[tid] - s;   // exclusive prefix of this thread's chunk
  for(int i=begin;i<end;i++){
    rowptr[i] = run; cursor[i] = run; run += deg[i];
  }
  if(tid == 255) rowptr[N] = part[255];
}

__global__ __launch_bounds__(256) void scatter_k(
    const float* __restrict__ pos, const float* __restrict__ shifts,
    const int* __restrict__ eidx, int* __restrict__ cursor,
    int* __restrict__ elist, int E)
{
  int e = blockIdx.x*256 + threadIdx.x;
  if(e >= E) return;
  int snd = eidx[e], rcv = eidx[E+e];
  float vx = pos[rcv*3+0]-pos[snd*3+0]+shifts[e*3+0];
  float vy = pos[rcv*3+1]-pos[snd*3+1]+shifts[e*3+1];
  float vz = pos[rcv*3+2]-pos[snd*3+2]+shifts[e*3+2];
  float r2 = vx*vx+vy*vy+vz*vz + 1e-12f;
  if(r2 < RMAXF*RMAXF){
    int p = atomicAdd(&cursor[rcv], 1);
    elist[p] = e;
  }
}

// ---------------- edge forward: one wave per node; A stored as f16 pairs --
__global__ __launch_bounds__(256) void fwd_tab(
    const float* __restrict__ pos, const float* __restrict__ shifts,
    const int* __restrict__ eidx, const float* __restrict__ h,
    const float* __restrict__ w_tab,
    const int* __restrict__ rowptr, const int* __restrict__ elist,
    unsigned int* __restrict__ Ah, int N, int E)
{
  int tid = threadIdx.x, ws4 = tid >> 6, lane = tid & 63;
  int n = blockIdx.x*4 + ws4;
  if(n >= N) return;
  int beg = rowptr[n], endp = rowptr[n+1];
  float acc[16];
  #pragma unroll
  for(int lm=0;lm<16;lm++) acc[lm] = 0.f;
  float px = pos[n*3+0], py = pos[n*3+1], pz = pos[n*3+2];
  for(int idx=beg; idx<endp; idx++){
    int e = elist[idx];
    int snd = eidx[e];
    float vx = px - pos[snd*3+0] + shifts[e*3+0];
    float vy = py - pos[snd*3+1] + shifts[e*3+1];
    float vz = pz - pos[snd*3+2] + shifts[e*3+2];
    float r = sqrtf(vx*vx+vy*vy+vz*vz + 1e-12f);
    float invr = 1.f/r;
    float Y[16]; sph16(vx*invr, vy*invr, vz*invr, Y);
    float rs = r*TAB_SCALE;
    int i0 = (int)rs; i0 = i0 < NPTS-2 ? i0 : NPTS-2;
    float fr = rs - (float)i0;
    const float* t0 = w_tab + i0*64 + lane;
    float w0 = t0[0], w1 = t0[64];
    float w = w0 + fr*(w1-w0);
    float wh = w * h[(size_t)snd*64+lane] * INV_AVG;
    #pragma unroll
    for(int lm=0;lm<16;lm++) acc[lm] += wh*Y[lm];
  }
  // pack lane-pairs (k even/odd) to f16x2 and store
  unsigned int* Ab = Ah + (size_t)n*512 + (lane>>1);
  #pragma unroll
  for(int lm=0;lm<16;lm++){
    float nb = __shfl_xor(acc[lm], 1, 64);
    if(!(lane&1)) Ab[lm*32] = pk16(acc[lm], nb);
  }
}

// ---------------- node forward: zero-LDS GEMV via uniform loads + v_dot2 --
// 2 waves per node: q=0 -> lm {1..8} (W1,W2); q=1 -> lm {0,9..15} (W0,W3).
// lane = output channel c. W columns in 64 packed-f16 VGPRs per wave.
__global__ __launch_bounds__(256) void node_fwd(
    const unsigned int* __restrict__ Ah,   // [N][16][32] f16 pairs
    const unsigned int* __restrict__ Wpc,  // [4][64][32]
    const float* __restrict__ W_prod, const float* __restrict__ w_ro,
    const int* __restrict__ batch, float* __restrict__ e_acc,
    unsigned int* __restrict__ gAm, int N) // [N][16][32] f16 pairs
{
  __shared__ float sS[4][64];
  __shared__ float sA0[2][64];
  int tid = threadIdx.x, wv = tid >> 6, lane = tid & 63;
  int q = wv & 1, hf = wv >> 1;
  int lA = q ? 0 : 1, lB = q ? 3 : 2;
  h2 WA[32], WB[32];
  {
    const uint4* pa = (const uint4*)(Wpc + lA*2048 + lane*32);
    const uint4* pb = (const uint4*)(Wpc + lB*2048 + lane*32);
    #pragma unroll
    for(int b=0;b<8;b++){
      uint4 ra = pa[b], rb = pb[b];
      WA[b*4+0]=as_h2(ra.x); WA[b*4+1]=as_h2(ra.y); WA[b*4+2]=as_h2(ra.z); WA[b*4+3]=as_h2(ra.w);
      WB[b*4+0]=as_h2(rb.x); WB[b*4+1]=as_h2(rb.y); WB[b*4+2]=as_h2(rb.z); WB[b*4+3]=as_h2(rb.w);
    }
  }
  float wp0 = W_prod[lane], wp1 = W_prod[64+lane], wp2 = W_prod[128+lane];
  float wr = w_ro[lane];
  int npair = (N+1) >> 1;
  for(int pr = blockIdx.x; pr < npair; pr += gridDim.x){
    int n = pr*2 + hf;
    bool alive = (n < N);
    float am[8];
    if(alive){
      #pragma unroll
      for(int j=0;j<8;j++){
        int lm = q ? ((j==0)?0:(8+j)) : (j+1);
        int off = __builtin_amdgcn_readfirstlane(n*512 + lm*32);
        const uint4* row = (const uint4*)(Ah + off);
        float acc = 0.f;
        bool useA = q ? (j==0) : (j<3);
        if(useA){
          #pragma unroll
          for(int b=0;b<8;b++){
            uint4 r = row[b];
            acc = fdot2(WA[b*4+0], as_h2(r.x), acc);
            acc = fdot2(WA[b*4+1], as_h2(r.y), acc);
            acc = fdot2(WA[b*4+2], as_h2(r.z), acc);
            acc = fdot2(WA[b*4+3], as_h2(r.w), acc);
          }
        } else {
          #pragma unroll
          for(int b=0;b<8;b++){
            uint4 r = row[b];
            acc = fdot2(WB[b*4+0], as_h2(r.x), acc);
            acc = fdot2(WB[b*4+1], as_h2(r.y), acc);
            acc = fdot2(WB[b*4+2], as_h2(r.z), acc);
            acc = fdot2(WB[b*4+3], as_h2(r.w), acc);
          }
        }
        am[j] = acc;
      }
      float sp = 0.f;
      #pragma unroll
      for(int j=0;j<8;j++) sp += am[j]*am[j];
      sS[wv][lane] = sp;
      if(q) sA0[hf][lane] = am[0];
    }
    __syncthreads();
    if(alive){
      float s_  = sS[wv][lane] + sS[wv^1][lane];
      float a0_ = sA0[hf][lane];
      if(q){
        float B = wp0*a0_ + wp1*s_ + wp2*a0_*s_;
        float v = B*wr;
        #pragma unroll
        for(int off=32; off; off>>=1) v += __shfl_xor(v, off, 64);
        if(lane==0) atomicAdd(&e_acc[batch[n]*2+1], v);
      }
      float gs = wr*(wp1 + wp2*a0_);
      #pragma unroll
      for(int j=0;j<8;j++){
        int lm = q ? ((j==0)?0:(8+j)) : (j+1);
        float g = gs*2.f*am[j];
        if(q && j==0) g += wr*(wp0 + wp2*s_);
        float nb = __shfl_xor(g, 1, 64);
        if(!(lane&1))
          gAm[n*512 + lm*32 + (lane>>1)] = pk16(g, nb);
      }
    }
    __syncthreads();
  }
}

// ---------------- node backward: gA = W^T-GEMV, zero-LDS, lane = k --------
__global__ __launch_bounds__(256) void node_bwd(
    const unsigned int* __restrict__ gAm,  // [N][16][32] f16 pairs
    const unsigned int* __restrict__ Wpr,  // [4][64][32]
    float* __restrict__ gA, int N)         // [N][16][64] f32 (overwrites Ah region)
{
  int tid = threadIdx.x, wv = tid >> 6, lane = tid & 63;
  int q = wv & 1, hf = wv >> 1;
  int lA = q ? 0 : 1, lB = q ? 3 : 2;
  h2 WA[32], WB[32];
  {
    const uint4* pa = (const uint4*)(Wpr + lA*2048 + lane*32);
    const uint4* pb = (const uint4*)(Wpr + lB*2048 + lane*32);
    #pragma unroll
    for(int b=0;b<8;b++){
      uint4 ra = pa[b], rb = pb[b];
      WA[b*4+0]=as_h2(ra.x); WA[b*4+1]=as_h2(ra.y); WA[b*4+2]=as_h2(ra.z); WA[b*4+3]=as_h2(ra.w);
      WB[b*4+0]=as_h2(rb.x); WB[b*4+1]=as_h2(rb.y); WB[b*4+2]=as_h2(rb.z); WB[b*4+3]=as_h2(rb.w);
    }
  }
  int npair = (N+1) >> 1;
  for(int pr = blockIdx.x; pr < npair; pr += gridDim.x){
    int n = pr*2 + hf;
    if(n >= N) continue;
    #pragma unroll
    for(int j=0;j<8;j++){
      int lm = q ? ((j==0)?0:(8+j)) : (j+1);
      int off = __builtin_amdgcn_readfirstlane(n*512 + lm*32);
      const uint4* row = (const uint4*)(gAm + off);
      float acc = 0.f;
      bool useA = q ? (j==0) : (j<3);
      if(useA){
        #pragma unroll
        for(int b=0;b<8;b++){
          uint4 r = row[b];
          acc = fdot2(WA[b*4+0], as_h2(r.x), acc);
          acc = fdot2(WA[b*4+1], as_h2(r.y), acc);
          acc = fdot2(WA[b*4+2], as_h2(r.z), acc);
          acc = fdot2(WA[b*4+3], as_h2(r.w), acc);
        }
      } else {
        #pragma unroll
        for(int b=0;b<8;b++){
          uint4 r = row[b];
          acc = fdot2(WB[b*4+0], as_h2(r.x), acc);
          acc = fdot2(WB[b*4+1], as_h2(r.y), acc);
          acc = fdot2(WB[b*4+2], as_h2(r.z), acc);
          acc = fdot2(WB[b*4+3], as_h2(r.w), acc);
        }
      }
      gA[(size_t)n*1024 + lm*64 + lane] = acc;
    }
  }
}

// ---------------- edge backward: one wave per node, table lookup ----------
__global__ __launch_bounds__(256) void bwd_tab(
    const float* __restrict__ pos, const float* __restrict__ shifts,
    const int* __restrict__ eidx, const float* __restrict__ h,
    const float* __restrict__ w_tab, const float* __restrict__ dw_tab,
    const float* __restrict__ gA,
    const int* __restrict__ rowptr, const int* __restrict__ elist,
    float* __restrict__ forces, int N, int E)
{
  int tid = threadIdx.x, ws4 = tid >> 6, lane = tid & 63;
  int n = blockIdx.x*4 + ws4;
  if(n >= N) return;
  int beg = rowptr[n], endp = rowptr[n+1];
  if(beg == endp) return;
  float gm[16];
  {
    const float* gb = gA + (size_t)n*1024 + lane;
    #pragma unroll
    for(int lm=0;lm<16;lm++) gm[lm] = gb[lm*64]*INV_AVG;
  }
  float px = pos[n*3+0], py = pos[n*3+1], pz = pos[n*3+2];
  float fx=0.f, fy=0.f, fz=0.f;
  const float c1=0.4886025119029199f, c2=1.0925484305920792f, c3=0.31539156525252005f;
  const float c4=0.5462742152960396f, c5=0.5900435899266435f, c6=2.890611442640554f;
  const float c7=0.4570457994644658f, c8=0.3731763325901154f, c9=1.445305721320277f;

  for(int idx=beg; idx<endp; idx++){
    int e = elist[idx];
    int snd = eidx[e];
    float vx = px - pos[snd*3+0] + shifts[e*3+0];
    float vy = py - pos[snd*3+1] + shifts[e*3+1];
    float vz = pz - pos[snd*3+2] + shifts[e*3+2];
    float r = sqrtf(vx*vx+vy*vy+vz*vz + 1e-12f);
    float invr = 1.f/r;
    float x=vx*invr, y=vy*invr, z=vz*invr;
    float Y[16]; sph16(x,y,z,Y);
    float rs = r*TAB_SCALE;
    int i0 = (int)rs; i0 = i0 < NPTS-2 ? i0 : NPTS-2;
    float fr = rs - (float)i0;
    const float* t0 = w_tab  + i0*64 + lane;
    const float* d0 = dw_tab + i0*64 + lane;
    float w    = t0[0] + fr*(t0[64]-t0[0]);
    float dwdr = d0[0] + fr*(d0[64]-d0[0]);
    float hk = h[(size_t)snd*64+lane];
    float wh = w*hk;
    float gw = 0.f;
    #pragma unroll
    for(int lm=0;lm<16;lm++) gw += gm[lm]*Y[lm];
    gw *= hk;
    float x2=x*x, y2=y*y, z2=z*z;
    float fz1 = 5.f*z2-1.f;
    float gxp = c1*gm[3] + c2*(y*gm[4] + z*gm[7]) + 2.f*c4*x*gm[8]
              + 6.f*c5*x*y*gm[9] + c6*y*z*gm[10] + c7*fz1*gm[13]
              + 2.f*c9*x*z*gm[14] + 3.f*c5*(x2-y2)*gm[15];
    float gyp = c1*gm[1] + c2*(x*gm[4] + z*gm[5]) - 2.f*c4*y*gm[8]
              + 3.f*c5*(x2-y2)*gm[9] + c6*x*z*gm[10] + c7*fz1*gm[11]
              - 2.f*c9*y*z*gm[14] - 6.f*c5*x*y*gm[15];
    float gzp = c1*gm[2] + c2*(y*gm[5] + x*gm[7]) + 6.f*c3*z*gm[6]
              + c6*x*y*gm[10] + 10.f*c7*y*z*gm[11] + c8*(15.f*z2-3.f)*gm[12]
              + 10.f*c7*x*z*gm[13] + c9*(x2-y2)*gm[14];
    float gx = gxp*wh*SQ4PI, gy = gyp*wh*SQ4PI, gz = gzp*wh*SQ4PI;
    float grp = gw*dwdr;
    #pragma unroll
    for(int off=32; off; off>>=1){
      gx  += __shfl_xor(gx,  off, 64);
      gy  += __shfl_xor(gy,  off, 64);
      gz  += __shfl_xor(gz,  off, 64);
      grp += __shfl_xor(grp, off, 64);
    }
    float udot = x*gx + y*gy + z*gz;
    float gvx = grp*x + (gx - udot*x)*invr;
    float gvy = grp*y + (gy - udot*y)*invr;
    float gvz = grp*z + (gz - udot*z)*invr;
    fx -= gvx; fy -= gvy; fz -= gvz;
    if(lane==0){
      atomicAdd(&forces[snd*3+0],  gvx);
      atomicAdd(&forces[snd*3+1],  gvy);
      atomicAdd(&forces[snd*3+2],  gvz);
    }
  }
  if(lane==0){
    atomicAdd(&forces[n*3+0], fx);
    atomicAdd(&forces[n*3+1], fy);
    atomicAdd(&forces[n*3+2], fz);
  }
}

// ---------------- finalize ---------------------------------------------
__global__ void fin_k(const float* __restrict__ e_acc, float* __restrict__ out, int G){
  int g = threadIdx.x;
  if(g < G){
    float e0 = e_acc[2*g], e1 = e_acc[2*g+1];
    out[g] = e0+e1;
    out[G + 2*g] = e0;
    out[G + 2*g+1] = e1;
  }
}

extern "C" void kernel_launch(void* const* d_in, const int* in_sizes, int n_in,
                              void* d_out, int out_size, void* d_ws, size_t ws_size,
                              hipStream_t stream) {
  const float* positions  = (const float*)d_in[0];
  const float* node_attrs = (const float*)d_in[1];
  const float* shifts     = (const float*)d_in[2];
  const float* W_embed    = (const float*)d_in[3];
  const float* at_en      = (const float*)d_in[4];
  const float* W_r1       = (const float*)d_in[5];
  const float* W_r2       = (const float*)d_in[6];
  const float* W_mix      = (const float*)d_in[7];
  const float* W_prod     = (const float*)d_in[8];
  const float* w_ro       = (const float*)d_in[9];
  const int*   edge_index = (const int*)d_in[10];
  const int*   batch      = (const int*)d_in[11];

  int N = in_sizes[0]/3;
  int E = in_sizes[10]/2;
  int G = (out_size - 3*N)/3;

  float* out    = (float*)d_out;
  float* bufA   = (float*)d_ws;                 // N*1024 f32: Ah (f16 pairs) then gA
  float* h      = bufA + (size_t)N*1024;        // N*64
  float* w_tab  = h + (size_t)N*64;             // NPTS*64
  float* dw_tab = w_tab + (size_t)NPTS*64;      // NPTS*64
  unsigned int* gAm = (unsigned int*)(dw_tab + (size_t)NPTS*64); // N*512
  unsigned int* Wpc = gAm + (size_t)N*512;      // 8192
  unsigned int* Wpr = Wpc + 8192;               // 8192
  float* eacc   = (float*)(Wpr + 8192);         // 2G
  int*   deg    = (int*)(eacc + 2*G);           // N
  int*   rowptr = deg + N;                      // N+1
  int*   cursor = rowptr + N + 1;               // N
  int*   elist  = cursor + N;                   // E

  unsigned int* Ah = (unsigned int*)bufA;

  hipMemsetAsync(d_out, 0, (size_t)out_size*sizeof(float), stream);
  hipMemsetAsync(eacc, 0, (size_t)2*G*sizeof(float), stream);
  hipMemsetAsync(deg, 0, (size_t)N*sizeof(int), stream);

  embed_k<<<N, 64, 0, stream>>>(node_attrs, W_embed, at_en, batch, h, eacc, N);
  tab_k<<<NPTS, 64, 0, stream>>>(W_r1, W_r2, w_tab, dw_tab);
  pack_k<<<32, 256, 0, stream>>>(W_mix, Wpc, Wpr);
  count_k<<<(E+255)/256, 256, 0, stream>>>(positions, shifts, edge_index, deg, E);
  scan_k<<<1, 256, 0, stream>>>(deg, rowptr, cursor, N);
  scatter_k<<<(E+255)/256, 256, 0, stream>>>(positions, shifts, edge_index, cursor, elist, E);
  fwd_tab<<<(N+3)/4, 256, 0, stream>>>(positions, shifts, edge_index, h, w_tab, rowptr, elist, Ah, N, E);
  node_fwd<<<2048, 256, 0, stream>>>(Ah, Wpc, W_prod, w_ro, batch, eacc, gAm, N);
  node_bwd<<<2048, 256, 0, stream>>>(gAm, Wpr, bufA, N);
  bwd_tab<<<(N+3)/4, 256, 0, stream>>>(positions, shifts, edge_index, h, w_tab, dw_tab, bufA, rowptr, elist, out + 3*G, N, E);
  fin_k<<<1, 64, 0, stream>>>(eacc, out, G);
}